// Round 11
// baseline (253.395 us; speedup 1.0000x reference)
//
#include <hip/hip_runtime.h>
#include <cstdint>
#include <cstddef>

#define FD 128
#define CO 64
#define NB 256     // partition blocks
#define NBINS 256  // buckets (node>>8); requires N <= 65536, src < 2^24

typedef short bf16x8 __attribute__((ext_vector_type(8)));
typedef float f32x4 __attribute__((ext_vector_type(4)));
typedef unsigned int uint32;
typedef unsigned char uint8;
typedef unsigned short ushort;

__device__ __forceinline__ ushort f2bf(float f) {
  unsigned u = __float_as_uint(f);
  unsigned r = u + 0x7fffu + ((u >> 16) & 1u);
  return (ushort)(r >> 16);
}
__device__ __forceinline__ float bf2f(ushort b) {
  return __uint_as_float((unsigned)b << 16);
}

// ---------------- CSR build: scan-based counting sort (no global atomics) ----------------

__global__ __launch_bounds__(256) void k_hist(const int* __restrict__ src,
                                              const int* __restrict__ dst,
                                              int* __restrict__ histD,
                                              int* __restrict__ histS,
                                              int E, int chunk) {
  __shared__ int hd[NBINS], hs[NBINS];
  int tid = threadIdx.x, blk = blockIdx.x;
  hd[tid] = 0;
  hs[tid] = 0;
  __syncthreads();
  int beg = blk * chunk;
  int end = min(E, beg + chunk);
  for (int e = beg + tid; e < end; e += 256) {
    atomicAdd(&hd[dst[e] >> 8], 1);
    atomicAdd(&hs[src[e] >> 8], 1);
  }
  __syncthreads();
  histD[tid * NB + blk] = hd[tid];  // bin-major layout
  histS[tid * NB + blk] = hs[tid];
}

__global__ __launch_bounds__(256) void k_ssum(int* __restrict__ a,
                                              int* __restrict__ b,
                                              int* __restrict__ bsums) {
  const int* p = blockIdx.y ? b : a;
  __shared__ int red[256];
  int tid = threadIdx.x;
  red[tid] = p[blockIdx.x * 256 + tid];
  __syncthreads();
  for (int o = 128; o > 0; o >>= 1) {
    if (tid < o) red[tid] += red[tid + o];
    __syncthreads();
  }
  if (tid == 0) bsums[blockIdx.y * 256 + blockIdx.x] = red[0];
}

__global__ __launch_bounds__(256) void k_sscan(int* __restrict__ bsums) {
  __shared__ int s[256];
  int tid = threadIdx.x;
  for (int r = 0; r < 2; r++) {
    int v = bsums[r * 256 + tid];
    s[tid] = v;
    __syncthreads();
    for (int o = 1; o < 256; o <<= 1) {
      int t = (tid >= o) ? s[tid - o] : 0;
      __syncthreads();
      s[tid] += t;
      __syncthreads();
    }
    bsums[r * 256 + tid] = s[tid] - v;  // exclusive
    __syncthreads();
  }
}

__global__ __launch_bounds__(256) void k_sapply(int* __restrict__ a,
                                                int* __restrict__ b,
                                                const int* __restrict__ bsums) {
  int* p = blockIdx.y ? b : a;
  int boff = bsums[blockIdx.y * 256 + blockIdx.x];
  __shared__ int s[256];
  int tid = threadIdx.x;
  int i = blockIdx.x * 256 + tid;
  int v = p[i];
  s[tid] = v;
  __syncthreads();
  for (int o = 1; o < 256; o <<= 1) {
    int t = (tid >= o) ? s[tid - o] : 0;
    __syncthreads();
    s[tid] += t;
    __syncthreads();
  }
  p[i] = boff + s[tid] - v;
}

__global__ __launch_bounds__(256) void k_scatter(const int* __restrict__ src,
                                                 const int* __restrict__ dst,
                                                 const int* __restrict__ offD,
                                                 const int* __restrict__ offS,
                                                 uint32* __restrict__ pk,
                                                 uint8* __restrict__ srcS8,
                                                 int E, int chunk) {
  __shared__ int runD[NBINS], runS[NBINS];
  int tid = threadIdx.x, blk = blockIdx.x;
  runD[tid] = offD[tid * NB + blk];
  runS[tid] = offS[tid * NB + blk];
  __syncthreads();
  int beg = blk * chunk;
  int end = min(E, beg + chunk);
  for (int e = beg + tid; e < end; e += 256) {
    int s = src[e], d = dst[e];
    int p = atomicAdd(&runD[d >> 8], 1);
    pk[p] = ((uint32)s << 8) | (uint32)(d & 255);
    int q = atomicAdd(&runS[s >> 8], 1);
    srcS8[q] = (uint8)(s & 255);
  }
}

__global__ __launch_bounds__(256) void k_bucket_dst(const uint32* __restrict__ pk,
                                                    const int* __restrict__ offD,
                                                    int* __restrict__ esrc,
                                                    int* __restrict__ row_ptr,
                                                    float* __restrict__ d_dst,
                                                    int N, int E) {
  __shared__ int cnt[NBINS], run[NBINS];
  int tid = threadIdx.x, bin = blockIdx.x;
  int start = offD[bin * NB];
  int end = (bin == NBINS - 1) ? E : offD[(bin + 1) * NB];
  cnt[tid] = 0;
  __syncthreads();
  for (int p = start + tid; p < end; p += 256) atomicAdd(&cnt[pk[p] & 255], 1);
  __syncthreads();
  int v = cnt[tid];
  run[tid] = v;
  __syncthreads();
  for (int o = 1; o < 256; o <<= 1) {
    int t = (tid >= o) ? run[tid - o] : 0;
    __syncthreads();
    run[tid] += t;
    __syncthreads();
  }
  int excl = run[tid] - v;
  int node = bin * 256 + tid;
  if (node < N) {
    row_ptr[node] = start + excl;
    d_dst[node] = rsqrtf((float)(v > 0 ? v : 1));
  }
  __syncthreads();
  run[tid] = start + excl;  // reuse as scatter cursor
  __syncthreads();
  for (int p = start + tid; p < end; p += 256) {
    uint32 v2 = pk[p];
    int slot = atomicAdd(&run[v2 & 255], 1);
    esrc[slot] = (int)(v2 >> 8);
  }
  if (bin == 0 && tid == 0) row_ptr[N] = E;
}

__global__ __launch_bounds__(256) void k_bucket_src(const uint8* __restrict__ srcS8,
                                                    const int* __restrict__ offS,
                                                    float* __restrict__ d_src,
                                                    int N, int E) {
  __shared__ int cnt[NBINS];
  int tid = threadIdx.x, bin = blockIdx.x;
  int start = offS[bin * NB];
  int end = (bin == NBINS - 1) ? E : offS[(bin + 1) * NB];
  cnt[tid] = 0;
  __syncthreads();
  for (int p = start + tid; p < end; p += 256) atomicAdd(&cnt[srcS8[p]], 1);
  __syncthreads();
  int node = bin * 256 + tid;
  if (node < N) {
    int v = cnt[tid];
    d_src[node] = rsqrtf((float)(v > 0 ? v : 1));
  }
}

// ---------------- weight pre-split: fp32 -> frag-packed bf16 hi/lo ----------------

__global__ __launch_bounds__(256) void k_wsplit(const float* __restrict__ W1,
                                                const float* __restrict__ W2,
                                                const float* __restrict__ W3,
                                                const float* __restrict__ Wr,
                                                const float* __restrict__ Wo,
                                                bf16x8* __restrict__ Whg,
                                                bf16x8* __restrict__ Wlg) {
  int idx = blockIdx.x * 256 + threadIdx.x;  // 9216 slots total
  if (idx >= 9216) return;
  int region = idx >> 11;
  if (idx >= 8192) region = 4;
  const float* W = (region == 0) ? W1 : (region == 1) ? W2 : (region == 2) ? W3
                   : (region == 3) ? Wr : Wo;
  int cols = (region < 4) ? FD : CO;
  int local = idx - region * 2048;
  int kc = local / cols, col = local - kc * cols;
  bf16x8 h, l;
#pragma unroll
  for (int j = 0; j < 8; j++) {
    float v = W[(size_t)(kc * 8 + j) * cols + col];
    ushort hb = f2bf(v);
    h[j] = (short)hb;
    l[j] = (short)f2bf(v - bf2f(hb));
  }
  Whg[idx] = h;
  Wlg[idx] = l;
}

// ---------------- dual GEMM: stage x once, two weight passes ----------------

__global__ __launch_bounds__(256) void k_gemm_dual(const float* __restrict__ x,
                                                   const bf16x8* __restrict__ Wh1,
                                                   const bf16x8* __restrict__ Wl1,
                                                   const float* __restrict__ d_src,
                                                   const bf16x8* __restrict__ Whr,
                                                   const bf16x8* __restrict__ Wlr,
                                                   const float* __restrict__ br,
                                                   ushort* __restrict__ out1,
                                                   ushort* __restrict__ out2,
                                                   int N) {
  __shared__ bf16x8 Ah[1024];  // [16 kc][64 row]
  int tid = threadIdx.x;
  int rowBase = blockIdx.x * 64;

#pragma unroll
  for (int t = 0; t < 4; t++) {
    int p = t * 256 + tid;
    int kc = p >> 6, row = p & 63;
    int gr = rowBase + row;
    bf16x8 h = {0, 0, 0, 0, 0, 0, 0, 0};
    if (gr < N) {
      const float4* A4 = (const float4*)(x + (size_t)gr * FD + kc * 8);
      float4 u = A4[0];
      float4 v = A4[1];
      float vals[8] = {u.x, u.y, u.z, u.w, v.x, v.y, v.z, v.w};
#pragma unroll
      for (int j = 0; j < 8; j++) h[j] = (short)f2bf(vals[j]);
    }
    Ah[kc * 64 + row] = h;
  }
  __syncthreads();

  int wv = tid >> 6, lane = tid & 63;
  int wr = (wv >> 1) * 32;
  int wc = (wv & 1) * 64;
  int lhi = lane >> 4, llo = lane & 15;

#pragma unroll
  for (int pass = 0; pass < 2; pass++) {
    const bf16x8* Wh = pass ? Whr : Wh1;
    const bf16x8* Wl = pass ? Wlr : Wl1;
    f32x4 acc[2][4] = {};
#pragma unroll
    for (int ks = 0; ks < 4; ks++) {
      int kcg = ks * 4 + lhi;
      int abase = kcg * 64 + wr + llo;
      bf16x8 a0 = Ah[abase];
      bf16x8 a1 = Ah[abase + 16];
      int bbase = kcg * FD + wc + llo;
#pragma unroll
      for (int nf = 0; nf < 4; nf++) {
        bf16x8 bh = Wh[bbase + nf * 16];
        bf16x8 bl = Wl[bbase + nf * 16];
        acc[0][nf] = __builtin_amdgcn_mfma_f32_16x16x32_bf16(a0, bh, acc[0][nf], 0, 0, 0);
        acc[1][nf] = __builtin_amdgcn_mfma_f32_16x16x32_bf16(a1, bh, acc[1][nf], 0, 0, 0);
        acc[0][nf] = __builtin_amdgcn_mfma_f32_16x16x32_bf16(a0, bl, acc[0][nf], 0, 0, 0);
        acc[1][nf] = __builtin_amdgcn_mfma_f32_16x16x32_bf16(a1, bl, acc[1][nf], 0, 0, 0);
      }
    }
#pragma unroll
    for (int nf = 0; nf < 4; nf++) {
      int col = wc + nf * 16 + llo;
      float bv = pass ? br[col] : 0.f;
#pragma unroll
      for (int mf = 0; mf < 2; mf++) {
#pragma unroll
        for (int r = 0; r < 4; r++) {
          int row = rowBase + wr + mf * 16 + lhi * 4 + r;
          if (row < N) {
            float v = acc[mf][nf][r];
            if (pass == 0) v *= d_src[row];
            else v += bv;
            ushort* o = pass ? out2 : out1;
            o[(size_t)row * FD + col] = f2bf(v);
          }
        }
      }
    }
  }
}

// ---------------- feature-quartered aggregation (L2-resident gather) ----------------
// Quarter q covers features [32q, 32q+32) = 3.2 MB of h -> fits one XCD L2.
// Grid quarter-major: blocks [q*nodeBlocks, (q+1)*nodeBlocks). Block = 256 thr;
// 4-lane sub-group per node (64 nodes/block); lane loads 16 B (8 features)/edge,
// 8 edges in flight. Epilogue: ×d_dst + bias [+res] relu [×d_src]; bf16 out.

template <bool RES, bool NEXTSCALE>
__global__ __launch_bounds__(256) void k_agg4(const ushort* __restrict__ h,
                                              const int* __restrict__ row_ptr,
                                              const int* __restrict__ esrc,
                                              const float* __restrict__ d_dst,
                                              const float* __restrict__ bias_in,
                                              const float* __restrict__ d_src,
                                              const ushort* __restrict__ res,
                                              ushort* __restrict__ out,
                                              int N, int nodeBlocks) {
  int blk = blockIdx.x;
  int q = blk / nodeBlocks;
  int nb = blk - q * nodeBlocks;
  int tid = threadIdx.x;
  int sub = tid >> 2, sl = tid & 3;
  int node = nb * 64 + sub;
  if (node >= N) return;
  int colSlot = q * 4 + sl;  // 16B slot index within 16-slot row
  const uint4* h16 = (const uint4*)h;

  // bias for features [q*32 + sl*8, +8)
  float4 bA = ((const float4*)bias_in)[q * 8 + sl * 2];
  float4 bB = ((const float4*)bias_in)[q * 8 + sl * 2 + 1];
  float bia[8] = {bA.x, bA.y, bA.z, bA.w, bB.x, bB.y, bB.z, bB.w};

  int beg = row_ptr[node], end = row_ptr[node + 1];
  float a[8] = {0.f, 0.f, 0.f, 0.f, 0.f, 0.f, 0.f, 0.f};
  int e = beg;
  for (; e + 8 <= end; e += 8) {
    int s[8];
#pragma unroll
    for (int j = 0; j < 8; j++) s[j] = esrc[e + j];
    uint4 v[8];
#pragma unroll
    for (int j = 0; j < 8; j++) v[j] = h16[(size_t)s[j] * 16 + colSlot];
#pragma unroll
    for (int j = 0; j < 8; j++) {
      a[0] += bf2f((ushort)(v[j].x & 0xffff));
      a[1] += bf2f((ushort)(v[j].x >> 16));
      a[2] += bf2f((ushort)(v[j].y & 0xffff));
      a[3] += bf2f((ushort)(v[j].y >> 16));
      a[4] += bf2f((ushort)(v[j].z & 0xffff));
      a[5] += bf2f((ushort)(v[j].z >> 16));
      a[6] += bf2f((ushort)(v[j].w & 0xffff));
      a[7] += bf2f((ushort)(v[j].w >> 16));
    }
  }
  for (; e < end; e++) {
    uint4 v = h16[(size_t)esrc[e] * 16 + colSlot];
    a[0] += bf2f((ushort)(v.x & 0xffff));
    a[1] += bf2f((ushort)(v.x >> 16));
    a[2] += bf2f((ushort)(v.y & 0xffff));
    a[3] += bf2f((ushort)(v.y >> 16));
    a[4] += bf2f((ushort)(v.z & 0xffff));
    a[5] += bf2f((ushort)(v.z >> 16));
    a[6] += bf2f((ushort)(v.w & 0xffff));
    a[7] += bf2f((ushort)(v.w >> 16));
  }

  float d = d_dst[node];
  float val[8];
#pragma unroll
  for (int j = 0; j < 8; j++) val[j] = a[j] * d + bia[j];
  if (RES) {
    uint4 rv = ((const uint4*)res)[(size_t)node * 16 + colSlot];
    val[0] += bf2f((ushort)(rv.x & 0xffff));
    val[1] += bf2f((ushort)(rv.x >> 16));
    val[2] += bf2f((ushort)(rv.y & 0xffff));
    val[3] += bf2f((ushort)(rv.y >> 16));
    val[4] += bf2f((ushort)(rv.z & 0xffff));
    val[5] += bf2f((ushort)(rv.z >> 16));
    val[6] += bf2f((ushort)(rv.w & 0xffff));
    val[7] += bf2f((ushort)(rv.w >> 16));
  }
#pragma unroll
  for (int j = 0; j < 8; j++) val[j] = fmaxf(val[j], 0.f);
  if (NEXTSCALE) {
    float sc = d_src[node];
#pragma unroll
    for (int j = 0; j < 8; j++) val[j] *= sc;
  }
  uint32 w0 = (uint32)f2bf(val[0]) | ((uint32)f2bf(val[1]) << 16);
  uint32 w1 = (uint32)f2bf(val[2]) | ((uint32)f2bf(val[3]) << 16);
  uint32 w2 = (uint32)f2bf(val[4]) | ((uint32)f2bf(val[5]) << 16);
  uint32 w3 = (uint32)f2bf(val[6]) | ((uint32)f2bf(val[7]) << 16);
  uint4 o;
  o.x = w0; o.y = w1; o.z = w2; o.w = w3;
  ((uint4*)out)[(size_t)node * 16 + colSlot] = o;
}

// ---------------- GEMM: out[N][NCW] = A(bf16) @ W (+bias) ----------------
// 64-row tile, A in LDS frag-packed, B frags direct from pre-split global.

template <int NCW, bool BIAS, bool OUTBF16>
__global__ __launch_bounds__(256) void k_gemmB(const ushort* __restrict__ A,
                                               const bf16x8* __restrict__ Wh,
                                               const bf16x8* __restrict__ Wl,
                                               const float* __restrict__ bias,
                                               void* __restrict__ outv, int N) {
  constexpr int NF = NCW / 32;
  __shared__ bf16x8 Ah[1024];  // [16 kc][64 row]
  int tid = threadIdx.x;
  int rowBase = blockIdx.x * 64;

#pragma unroll
  for (int t = 0; t < 4; t++) {
    int p = t * 256 + tid;
    int kc = p >> 6, row = p & 63;
    int gr = rowBase + row;
    bf16x8 h = {0, 0, 0, 0, 0, 0, 0, 0};
    if (gr < N) h = *(const bf16x8*)(A + (size_t)gr * FD + kc * 8);
    Ah[kc * 64 + row] = h;
  }
  __syncthreads();

  int wv = tid >> 6, lane = tid & 63;
  int wr = (wv >> 1) * 32;
  int wc = (wv & 1) * (NCW / 2);
  int lhi = lane >> 4, llo = lane & 15;
  f32x4 acc[2][NF] = {};

#pragma unroll
  for (int ks = 0; ks < 4; ks++) {
    int kcg = ks * 4 + lhi;
    int abase = kcg * 64 + wr + llo;
    bf16x8 a0 = Ah[abase];
    bf16x8 a1 = Ah[abase + 16];
    int bbase = kcg * NCW + wc + llo;
#pragma unroll
    for (int nf = 0; nf < NF; nf++) {
      bf16x8 bh = Wh[bbase + nf * 16];
      bf16x8 bl = Wl[bbase + nf * 16];
      acc[0][nf] = __builtin_amdgcn_mfma_f32_16x16x32_bf16(a0, bh, acc[0][nf], 0, 0, 0);
      acc[1][nf] = __builtin_amdgcn_mfma_f32_16x16x32_bf16(a1, bh, acc[1][nf], 0, 0, 0);
      acc[0][nf] = __builtin_amdgcn_mfma_f32_16x16x32_bf16(a0, bl, acc[0][nf], 0, 0, 0);
      acc[1][nf] = __builtin_amdgcn_mfma_f32_16x16x32_bf16(a1, bl, acc[1][nf], 0, 0, 0);
    }
  }

#pragma unroll
  for (int nf = 0; nf < NF; nf++) {
    int col = wc + nf * 16 + llo;
    float bv = BIAS ? bias[col] : 0.f;
#pragma unroll
    for (int mf = 0; mf < 2; mf++) {
#pragma unroll
      for (int r = 0; r < 4; r++) {
        int row = rowBase + wr + mf * 16 + lhi * 4 + r;
        if (row < N) {
          float v = acc[mf][nf][r] + bv;
          if (OUTBF16)
            ((ushort*)outv)[(size_t)row * NCW + col] = f2bf(v);
          else
            ((float*)outv)[(size_t)row * NCW + col] = v;
        }
      }
    }
  }
}

// ---------------- launch ----------------

extern "C" void kernel_launch(void* const* d_in, const int* in_sizes, int n_in,
                              void* d_out, int out_size, void* d_ws, size_t ws_size,
                              hipStream_t stream) {
  (void)n_in; (void)out_size; (void)ws_size;
  const float* x  = (const float*)d_in[0];
  const int*   src = (const int*)d_in[1];
  const int*   dst = (const int*)d_in[2];
  const float* W1 = (const float*)d_in[3];
  const float* b1 = (const float*)d_in[4];
  const float* W2 = (const float*)d_in[5];
  const float* b2 = (const float*)d_in[6];
  const float* W3 = (const float*)d_in[7];
  const float* b3 = (const float*)d_in[8];
  const float* Wr = (const float*)d_in[9];
  const float* br = (const float*)d_in[10];
  const float* Wo = (const float*)d_in[11];
  const float* bo = (const float*)d_in[12];
  float* out = (float*)d_out;

  const int N = in_sizes[0] / FD;
  const int E = in_sizes[1];

  char* ws = (char*)d_ws;
  size_t off = 0;
  auto alloc = [&](size_t bytes) -> void* {
    void* p = ws + off;
    off += (bytes + 255) & ~size_t(255);
    return p;
  };
  int* histD   = (int*)alloc((size_t)NBINS * NB * 4);
  int* histS   = (int*)alloc((size_t)NBINS * NB * 4);
  int* bsums   = (int*)alloc(2 * 256 * 4);
  uint32* pk   = (uint32*)alloc((size_t)E * 4);
  uint8* srcS8 = (uint8*)alloc((size_t)E);
  int* esrc    = (int*)alloc((size_t)E * 4);
  int* row_ptr = (int*)alloc((size_t)(N + 1) * 4);
  float* d_src = (float*)alloc((size_t)N * 4);
  float* d_dst = (float*)alloc((size_t)N * 4);
  bf16x8* Whg  = (bf16x8*)alloc(9216 * 16);
  bf16x8* Wlg  = (bf16x8*)alloc(9216 * 16);
  ushort* tb0  = (ushort*)alloc((size_t)N * FD * 2);
  ushort* tb1  = (ushort*)alloc((size_t)N * FD * 2);
  ushort* tba  = (ushort*)alloc((size_t)N * FD * 2);
  ushort* resb = (ushort*)alloc((size_t)N * FD * 2);

  int chunk = (E + NB - 1) / NB;
  dim3 gScan(256, 2);

  k_wsplit<<<36, 256, 0, stream>>>(W1, W2, W3, Wr, Wo, Whg, Wlg);
  k_hist<<<NB, 256, 0, stream>>>(src, dst, histD, histS, E, chunk);
  k_ssum<<<gScan, 256, 0, stream>>>(histD, histS, bsums);
  k_sscan<<<1, 256, 0, stream>>>(bsums);
  k_sapply<<<gScan, 256, 0, stream>>>(histD, histS, bsums);
  k_scatter<<<NB, 256, 0, stream>>>(src, dst, histD, histS, pk, srcS8, E, chunk);
  k_bucket_dst<<<NBINS, 256, 0, stream>>>(pk, histD, esrc, row_ptr, d_dst, N, E);
  k_bucket_src<<<NBINS, 256, 0, stream>>>(srcS8, histS, d_src, N, E);

  int gG = (N + 63) / 64;
  int nodeBlocks = (N + 63) / 64;
  int gA = nodeBlocks * 4;  // quarter-major

  const bf16x8* Wh1 = Whg;
  const bf16x8* Wh2 = Whg + 2048;
  const bf16x8* Wh3 = Whg + 4096;
  const bf16x8* Whr = Whg + 6144;
  const bf16x8* Who = Whg + 8192;
  const bf16x8* Wl1 = Wlg;
  const bf16x8* Wl2 = Wlg + 2048;
  const bf16x8* Wl3 = Wlg + 4096;
  const bf16x8* Wlr = Wlg + 6144;
  const bf16x8* Wlo = Wlg + 8192;

  // tb0 = bf16(d_src ⊙ (x@W1)); resb = bf16(x@Wr + br)
  k_gemm_dual<<<gG, 256, 0, stream>>>(x, Wh1, Wl1, d_src, Whr, Wlr, br, tb0, resb, N);
  // layer 1 conv epilogue + next scale: tba = d_src ⊙ relu(d_dst⊙Agg(tb0) + b1)
  k_agg4<false, true><<<gA, 256, 0, stream>>>(tb0, row_ptr, esrc, d_dst, b1, d_src,
                                              nullptr, tba, N, nodeBlocks);
  // tb1 = tba @ W2
  k_gemmB<FD, false, true><<<gG, 256, 0, stream>>>(tba, Wh2, Wl2, nullptr, tb1, N);
  // layer 2: tba = d_src ⊙ relu(d_dst⊙Agg(tb1) + b2)
  k_agg4<false, true><<<gA, 256, 0, stream>>>(tb1, row_ptr, esrc, d_dst, b2, d_src,
                                              nullptr, tba, N, nodeBlocks);
  // tb0 = tba @ W3
  k_gemmB<FD, false, true><<<gG, 256, 0, stream>>>(tba, Wh3, Wl3, nullptr, tb0, N);
  // layer 3: tba = relu(d_dst⊙Agg(tb0) + b3 + resb)
  k_agg4<true, false><<<gA, 256, 0, stream>>>(tb0, row_ptr, esrc, d_dst, b3, nullptr,
                                              resb, tba, N, nodeBlocks);
  // out = tba @ Wo + bo  (fp32)
  k_gemmB<CO, true, false><<<gG, 256, 0, stream>>>(tba, Who, Wlo, bo, out, N);
}

// Round 12
// 239.186 us; speedup vs baseline: 1.0594x; 1.0594x over previous
//
#include <hip/hip_runtime.h>
#include <cstdint>
#include <cstddef>

#define FD 128
#define CO 64
#define NB 256     // partition blocks
#define NBINS 256  // buckets (node>>8); requires N <= 65536
#define NXCD 8

typedef short bf16x8 __attribute__((ext_vector_type(8)));
typedef float f32x4 __attribute__((ext_vector_type(4)));
typedef unsigned int uint32;
typedef unsigned char uint8;
typedef unsigned short ushort;

__device__ __forceinline__ ushort f2bf(float f) {
  unsigned u = __float_as_uint(f);
  unsigned r = u + 0x7fffu + ((u >> 16) & 1u);
  return (ushort)(r >> 16);
}
__device__ __forceinline__ float bf2f(ushort b) {
  return __uint_as_float((unsigned)b << 16);
}

// ---------------- CSR build: scan-based counting sort (no global atomics) ----------------

__global__ __launch_bounds__(256) void k_hist(const int* __restrict__ src,
                                              const int* __restrict__ dst,
                                              int* __restrict__ histD,
                                              int* __restrict__ histS,
                                              int E, int chunk) {
  __shared__ int hd[NBINS], hs[NBINS];
  int tid = threadIdx.x, blk = blockIdx.x;
  hd[tid] = 0;
  hs[tid] = 0;
  __syncthreads();
  int beg = blk * chunk;
  int end = min(E, beg + chunk);
  for (int e = beg + tid; e < end; e += 256) {
    atomicAdd(&hd[dst[e] >> 8], 1);
    atomicAdd(&hs[src[e] >> 8], 1);
  }
  __syncthreads();
  histD[tid * NB + blk] = hd[tid];  // bin-major layout
  histS[tid * NB + blk] = hs[tid];
}

__global__ __launch_bounds__(256) void k_ssum(int* __restrict__ a,
                                              int* __restrict__ b,
                                              int* __restrict__ bsums) {
  const int* p = blockIdx.y ? b : a;
  __shared__ int red[256];
  int tid = threadIdx.x;
  red[tid] = p[blockIdx.x * 256 + tid];
  __syncthreads();
  for (int o = 128; o > 0; o >>= 1) {
    if (tid < o) red[tid] += red[tid + o];
    __syncthreads();
  }
  if (tid == 0) bsums[blockIdx.y * 256 + blockIdx.x] = red[0];
}

__global__ __launch_bounds__(256) void k_sscan(int* __restrict__ bsums) {
  __shared__ int s[256];
  int tid = threadIdx.x;
  for (int r = 0; r < 2; r++) {
    int v = bsums[r * 256 + tid];
    s[tid] = v;
    __syncthreads();
    for (int o = 1; o < 256; o <<= 1) {
      int t = (tid >= o) ? s[tid - o] : 0;
      __syncthreads();
      s[tid] += t;
      __syncthreads();
    }
    bsums[r * 256 + tid] = s[tid] - v;  // exclusive
    __syncthreads();
  }
}

__global__ __launch_bounds__(256) void k_sapply(int* __restrict__ a,
                                                int* __restrict__ b,
                                                const int* __restrict__ bsums) {
  int* p = blockIdx.y ? b : a;
  int boff = bsums[blockIdx.y * 256 + blockIdx.x];
  __shared__ int s[256];
  int tid = threadIdx.x;
  int i = blockIdx.x * 256 + tid;
  int v = p[i];
  s[tid] = v;
  __syncthreads();
  for (int o = 1; o < 256; o <<= 1) {
    int t = (tid >= o) ? s[tid - o] : 0;
    __syncthreads();
    s[tid] += t;
    __syncthreads();
  }
  p[i] = boff + s[tid] - v;
}

__global__ __launch_bounds__(256) void k_scatter(const int* __restrict__ src,
                                                 const int* __restrict__ dst,
                                                 const int* __restrict__ offD,
                                                 const int* __restrict__ offS,
                                                 uint32* __restrict__ pk,
                                                 uint8* __restrict__ srcS8,
                                                 int E, int chunk) {
  __shared__ int runD[NBINS], runS[NBINS];
  int tid = threadIdx.x, blk = blockIdx.x;
  runD[tid] = offD[tid * NB + blk];
  runS[tid] = offS[tid * NB + blk];
  __syncthreads();
  int beg = blk * chunk;
  int end = min(E, beg + chunk);
  for (int e = beg + tid; e < end; e += 256) {
    int s = src[e], d = dst[e];
    int p = atomicAdd(&runD[d >> 8], 1);
    pk[p] = ((uint32)s << 8) | (uint32)(d & 255);
    int q = atomicAdd(&runS[s >> 8], 1);
    srcS8[q] = (uint8)(s & 255);
  }
}

// per-bucket: count deg_in -> row_ptr, d_dst; scatter src ids (uint16) into CSR esrc
__global__ __launch_bounds__(256) void k_bucket_dst(const uint32* __restrict__ pk,
                                                    const int* __restrict__ offD,
                                                    ushort* __restrict__ esrc,
                                                    int* __restrict__ row_ptr,
                                                    float* __restrict__ d_dst,
                                                    int N, int E) {
  __shared__ int cnt[NBINS], run[NBINS];
  int tid = threadIdx.x, bin = blockIdx.x;
  int start = offD[bin * NB];
  int end = (bin == NBINS - 1) ? E : offD[(bin + 1) * NB];
  cnt[tid] = 0;
  __syncthreads();
  for (int p = start + tid; p < end; p += 256) atomicAdd(&cnt[pk[p] & 255], 1);
  __syncthreads();
  int v = cnt[tid];
  run[tid] = v;
  __syncthreads();
  for (int o = 1; o < 256; o <<= 1) {
    int t = (tid >= o) ? run[tid - o] : 0;
    __syncthreads();
    run[tid] += t;
    __syncthreads();
  }
  int excl = run[tid] - v;
  int node = bin * 256 + tid;
  if (node < N) {
    row_ptr[node] = start + excl;
    d_dst[node] = rsqrtf((float)(v > 0 ? v : 1));
  }
  __syncthreads();
  run[tid] = start + excl;  // reuse as scatter cursor
  __syncthreads();
  for (int p = start + tid; p < end; p += 256) {
    uint32 v2 = pk[p];
    int slot = atomicAdd(&run[v2 & 255], 1);
    esrc[slot] = (ushort)(v2 >> 8);
  }
  if (bin == 0 && tid == 0) row_ptr[N] = E;
}

__global__ __launch_bounds__(256) void k_bucket_src(const uint8* __restrict__ srcS8,
                                                    const int* __restrict__ offS,
                                                    float* __restrict__ d_src,
                                                    int N, int E) {
  __shared__ int cnt[NBINS];
  int tid = threadIdx.x, bin = blockIdx.x;
  int start = offS[bin * NB];
  int end = (bin == NBINS - 1) ? E : offS[(bin + 1) * NB];
  cnt[tid] = 0;
  __syncthreads();
  for (int p = start + tid; p < end; p += 256) atomicAdd(&cnt[srcS8[p]], 1);
  __syncthreads();
  int node = bin * 256 + tid;
  if (node < N) {
    int v = cnt[tid];
    d_src[node] = rsqrtf((float)(v > 0 ? v : 1));
  }
}

// ---------------- weight pre-split: fp32 -> frag-packed bf16 hi/lo ----------------

__global__ __launch_bounds__(256) void k_wsplit(const float* __restrict__ W1,
                                                const float* __restrict__ W2,
                                                const float* __restrict__ W3,
                                                const float* __restrict__ Wr,
                                                const float* __restrict__ Wo,
                                                bf16x8* __restrict__ Whg,
                                                bf16x8* __restrict__ Wlg) {
  int idx = blockIdx.x * 256 + threadIdx.x;  // 9216 slots total
  if (idx >= 9216) return;
  int region = idx >> 11;
  if (idx >= 8192) region = 4;
  const float* W = (region == 0) ? W1 : (region == 1) ? W2 : (region == 2) ? W3
                   : (region == 3) ? Wr : Wo;
  int cols = (region < 4) ? FD : CO;
  int local = idx - region * 2048;
  int kc = local / cols, col = local - kc * cols;
  bf16x8 h, l;
#pragma unroll
  for (int j = 0; j < 8; j++) {
    float v = W[(size_t)(kc * 8 + j) * cols + col];
    ushort hb = f2bf(v);
    h[j] = (short)hb;
    l[j] = (short)f2bf(v - bf2f(hb));
  }
  Whg[idx] = h;
  Wlg[idx] = l;
}

// ---------------- dual GEMM: stage x once, two weight passes ----------------

__global__ __launch_bounds__(256) void k_gemm_dual(const float* __restrict__ x,
                                                   const bf16x8* __restrict__ Wh1,
                                                   const bf16x8* __restrict__ Wl1,
                                                   const float* __restrict__ d_src,
                                                   const bf16x8* __restrict__ Whr,
                                                   const bf16x8* __restrict__ Wlr,
                                                   const float* __restrict__ br,
                                                   ushort* __restrict__ out1,
                                                   ushort* __restrict__ out2,
                                                   int N) {
  __shared__ bf16x8 Ah[1024];  // [16 kc][64 row]
  int tid = threadIdx.x;
  int rowBase = blockIdx.x * 64;

#pragma unroll
  for (int t = 0; t < 4; t++) {
    int p = t * 256 + tid;
    int kc = p >> 6, row = p & 63;
    int gr = rowBase + row;
    bf16x8 h = {0, 0, 0, 0, 0, 0, 0, 0};
    if (gr < N) {
      const float4* A4 = (const float4*)(x + (size_t)gr * FD + kc * 8);
      float4 u = A4[0];
      float4 v = A4[1];
      float vals[8] = {u.x, u.y, u.z, u.w, v.x, v.y, v.z, v.w};
#pragma unroll
      for (int j = 0; j < 8; j++) h[j] = (short)f2bf(vals[j]);
    }
    Ah[kc * 64 + row] = h;
  }
  __syncthreads();

  int wv = tid >> 6, lane = tid & 63;
  int wr = (wv >> 1) * 32;
  int wc = (wv & 1) * 64;
  int lhi = lane >> 4, llo = lane & 15;

#pragma unroll
  for (int pass = 0; pass < 2; pass++) {
    const bf16x8* Wh = pass ? Whr : Wh1;
    const bf16x8* Wl = pass ? Wlr : Wl1;
    f32x4 acc[2][4] = {};
#pragma unroll
    for (int ks = 0; ks < 4; ks++) {
      int kcg = ks * 4 + lhi;
      int abase = kcg * 64 + wr + llo;
      bf16x8 a0 = Ah[abase];
      bf16x8 a1 = Ah[abase + 16];
      int bbase = kcg * FD + wc + llo;
#pragma unroll
      for (int nf = 0; nf < 4; nf++) {
        bf16x8 bh = Wh[bbase + nf * 16];
        bf16x8 bl = Wl[bbase + nf * 16];
        acc[0][nf] = __builtin_amdgcn_mfma_f32_16x16x32_bf16(a0, bh, acc[0][nf], 0, 0, 0);
        acc[1][nf] = __builtin_amdgcn_mfma_f32_16x16x32_bf16(a1, bh, acc[1][nf], 0, 0, 0);
        acc[0][nf] = __builtin_amdgcn_mfma_f32_16x16x32_bf16(a0, bl, acc[0][nf], 0, 0, 0);
        acc[1][nf] = __builtin_amdgcn_mfma_f32_16x16x32_bf16(a1, bl, acc[1][nf], 0, 0, 0);
      }
    }
#pragma unroll
    for (int nf = 0; nf < 4; nf++) {
      int col = wc + nf * 16 + llo;
      float bv = pass ? br[col] : 0.f;
#pragma unroll
      for (int mf = 0; mf < 2; mf++) {
#pragma unroll
        for (int r = 0; r < 4; r++) {
          int row = rowBase + wr + mf * 16 + lhi * 4 + r;
          if (row < N) {
            float v = acc[mf][nf][r];
            if (pass == 0) v *= d_src[row];
            else v += bv;
            ushort* o = pass ? out2 : out1;
            o[(size_t)row * FD + col] = f2bf(v);
          }
        }
      }
    }
  }
}

// ---------------- feature-quartered aggregation, XCD-pinned quarters ----------------
// Quarter q (features [32q,32q+32) = 3.2 MB of h) is processed ONLY by blocks
// landing on XCDs {2q, 2q+1} (blockIdx -> XCD = blockIdx % 8 round-robin), so
// the slice is L2-resident per XCD. 4-lane sub-group per node; 16B load/edge;
// 8 edges in flight. Epilogue: ×d_dst + bias [+res] relu [×d_src]; bf16 out.

template <bool RES, bool NEXTSCALE>
__global__ __launch_bounds__(256) void k_agg4(const ushort* __restrict__ h,
                                              const int* __restrict__ row_ptr,
                                              const ushort* __restrict__ esrc,
                                              const float* __restrict__ d_dst,
                                              const float* __restrict__ bias_in,
                                              const float* __restrict__ d_src,
                                              const ushort* __restrict__ res,
                                              ushort* __restrict__ out,
                                              int N, int nodeBlocks) {
  int b = blockIdx.x;
  int q = (b & 7) >> 1;              // quarter <- XCD pair
  int nb = (b >> 3) * 2 + (b & 1);   // node-block within quarter
  if (nb >= nodeBlocks) return;
  int tid = threadIdx.x;
  int sub = tid >> 2, sl = tid & 3;
  int node = nb * 64 + sub;
  if (node >= N) return;
  int colSlot = q * 4 + sl;  // 16B slot within 16-slot row
  const uint4* h16 = (const uint4*)h;

  // bias for features [q*32 + sl*8, +8)
  float4 bA = ((const float4*)bias_in)[q * 8 + sl * 2];
  float4 bB = ((const float4*)bias_in)[q * 8 + sl * 2 + 1];
  float bia[8] = {bA.x, bA.y, bA.z, bA.w, bB.x, bB.y, bB.z, bB.w};

  int beg = row_ptr[node], end = row_ptr[node + 1];
  float a[8] = {0.f, 0.f, 0.f, 0.f, 0.f, 0.f, 0.f, 0.f};
  int e = beg;
  for (; e + 8 <= end; e += 8) {
    int s[8];
#pragma unroll
    for (int j = 0; j < 8; j++) s[j] = esrc[e + j];
    uint4 v[8];
#pragma unroll
    for (int j = 0; j < 8; j++) v[j] = h16[(size_t)s[j] * 16 + colSlot];
#pragma unroll
    for (int j = 0; j < 8; j++) {
      a[0] += bf2f((ushort)(v[j].x & 0xffff));
      a[1] += bf2f((ushort)(v[j].x >> 16));
      a[2] += bf2f((ushort)(v[j].y & 0xffff));
      a[3] += bf2f((ushort)(v[j].y >> 16));
      a[4] += bf2f((ushort)(v[j].z & 0xffff));
      a[5] += bf2f((ushort)(v[j].z >> 16));
      a[6] += bf2f((ushort)(v[j].w & 0xffff));
      a[7] += bf2f((ushort)(v[j].w >> 16));
    }
  }
  for (; e < end; e++) {
    uint4 v = h16[(size_t)esrc[e] * 16 + colSlot];
    a[0] += bf2f((ushort)(v.x & 0xffff));
    a[1] += bf2f((ushort)(v.x >> 16));
    a[2] += bf2f((ushort)(v.y & 0xffff));
    a[3] += bf2f((ushort)(v.y >> 16));
    a[4] += bf2f((ushort)(v.z & 0xffff));
    a[5] += bf2f((ushort)(v.z >> 16));
    a[6] += bf2f((ushort)(v.w & 0xffff));
    a[7] += bf2f((ushort)(v.w >> 16));
  }

  float d = d_dst[node];
  float val[8];
#pragma unroll
  for (int j = 0; j < 8; j++) val[j] = a[j] * d + bia[j];
  if (RES) {
    uint4 rv = ((const uint4*)res)[(size_t)node * 16 + colSlot];
    val[0] += bf2f((ushort)(rv.x & 0xffff));
    val[1] += bf2f((ushort)(rv.x >> 16));
    val[2] += bf2f((ushort)(rv.y & 0xffff));
    val[3] += bf2f((ushort)(rv.y >> 16));
    val[4] += bf2f((ushort)(rv.z & 0xffff));
    val[5] += bf2f((ushort)(rv.z >> 16));
    val[6] += bf2f((ushort)(rv.w & 0xffff));
    val[7] += bf2f((ushort)(rv.w >> 16));
  }
#pragma unroll
  for (int j = 0; j < 8; j++) val[j] = fmaxf(val[j], 0.f);
  if (NEXTSCALE) {
    float sc = d_src[node];
#pragma unroll
    for (int j = 0; j < 8; j++) val[j] *= sc;
  }
  uint32 w0 = (uint32)f2bf(val[0]) | ((uint32)f2bf(val[1]) << 16);
  uint32 w1 = (uint32)f2bf(val[2]) | ((uint32)f2bf(val[3]) << 16);
  uint32 w2 = (uint32)f2bf(val[4]) | ((uint32)f2bf(val[5]) << 16);
  uint32 w3 = (uint32)f2bf(val[6]) | ((uint32)f2bf(val[7]) << 16);
  uint4 o;
  o.x = w0; o.y = w1; o.z = w2; o.w = w3;
  ((uint4*)out)[(size_t)node * 16 + colSlot] = o;
}

// ---------------- GEMM: out[N][NCW] = A(bf16) @ W (+bias) ----------------

template <int NCW, bool BIAS, bool OUTBF16>
__global__ __launch_bounds__(256) void k_gemmB(const ushort* __restrict__ A,
                                               const bf16x8* __restrict__ Wh,
                                               const bf16x8* __restrict__ Wl,
                                               const float* __restrict__ bias,
                                               void* __restrict__ outv, int N) {
  constexpr int NF = NCW / 32;
  __shared__ bf16x8 Ah[1024];  // [16 kc][64 row]
  int tid = threadIdx.x;
  int rowBase = blockIdx.x * 64;

#pragma unroll
  for (int t = 0; t < 4; t++) {
    int p = t * 256 + tid;
    int kc = p >> 6, row = p & 63;
    int gr = rowBase + row;
    bf16x8 h = {0, 0, 0, 0, 0, 0, 0, 0};
    if (gr < N) h = *(const bf16x8*)(A + (size_t)gr * FD + kc * 8);
    Ah[kc * 64 + row] = h;
  }
  __syncthreads();

  int wv = tid >> 6, lane = tid & 63;
  int wr = (wv >> 1) * 32;
  int wc = (wv & 1) * (NCW / 2);
  int lhi = lane >> 4, llo = lane & 15;
  f32x4 acc[2][NF] = {};

#pragma unroll
  for (int ks = 0; ks < 4; ks++) {
    int kcg = ks * 4 + lhi;
    int abase = kcg * 64 + wr + llo;
    bf16x8 a0 = Ah[abase];
    bf16x8 a1 = Ah[abase + 16];
    int bbase = kcg * NCW + wc + llo;
#pragma unroll
    for (int nf = 0; nf < NF; nf++) {
      bf16x8 bh = Wh[bbase + nf * 16];
      bf16x8 bl = Wl[bbase + nf * 16];
      acc[0][nf] = __builtin_amdgcn_mfma_f32_16x16x32_bf16(a0, bh, acc[0][nf], 0, 0, 0);
      acc[1][nf] = __builtin_amdgcn_mfma_f32_16x16x32_bf16(a1, bh, acc[1][nf], 0, 0, 0);
      acc[0][nf] = __builtin_amdgcn_mfma_f32_16x16x32_bf16(a0, bl, acc[0][nf], 0, 0, 0);
      acc[1][nf] = __builtin_amdgcn_mfma_f32_16x16x32_bf16(a1, bl, acc[1][nf], 0, 0, 0);
    }
  }

#pragma unroll
  for (int nf = 0; nf < NF; nf++) {
    int col = wc + nf * 16 + llo;
    float bv = BIAS ? bias[col] : 0.f;
#pragma unroll
    for (int mf = 0; mf < 2; mf++) {
#pragma unroll
      for (int r = 0; r < 4; r++) {
        int row = rowBase + wr + mf * 16 + lhi * 4 + r;
        if (row < N) {
          float v = acc[mf][nf][r] + bv;
          if (OUTBF16)
            ((ushort*)outv)[(size_t)row * NCW + col] = f2bf(v);
          else
            ((float*)outv)[(size_t)row * NCW + col] = v;
        }
      }
    }
  }
}

// ---------------- launch ----------------

extern "C" void kernel_launch(void* const* d_in, const int* in_sizes, int n_in,
                              void* d_out, int out_size, void* d_ws, size_t ws_size,
                              hipStream_t stream) {
  (void)n_in; (void)out_size; (void)ws_size;
  const float* x  = (const float*)d_in[0];
  const int*   src = (const int*)d_in[1];
  const int*   dst = (const int*)d_in[2];
  const float* W1 = (const float*)d_in[3];
  const float* b1 = (const float*)d_in[4];
  const float* W2 = (const float*)d_in[5];
  const float* b2 = (const float*)d_in[6];
  const float* W3 = (const float*)d_in[7];
  const float* b3 = (const float*)d_in[8];
  const float* Wr = (const float*)d_in[9];
  const float* br = (const float*)d_in[10];
  const float* Wo = (const float*)d_in[11];
  const float* bo = (const float*)d_in[12];
  float* out = (float*)d_out;

  const int N = in_sizes[0] / FD;
  const int E = in_sizes[1];

  char* ws = (char*)d_ws;
  size_t off = 0;
  auto alloc = [&](size_t bytes) -> void* {
    void* p = ws + off;
    off += (bytes + 255) & ~size_t(255);
    return p;
  };
  int* histD   = (int*)alloc((size_t)NBINS * NB * 4);
  int* histS   = (int*)alloc((size_t)NBINS * NB * 4);
  int* bsums   = (int*)alloc(2 * 256 * 4);
  uint32* pk   = (uint32*)alloc((size_t)E * 4);
  uint8* srcS8 = (uint8*)alloc((size_t)E);
  ushort* esrc = (ushort*)alloc((size_t)E * 2);
  int* row_ptr = (int*)alloc((size_t)(N + 1) * 4);
  float* d_src = (float*)alloc((size_t)N * 4);
  float* d_dst = (float*)alloc((size_t)N * 4);
  bf16x8* Whg  = (bf16x8*)alloc(9216 * 16);
  bf16x8* Wlg  = (bf16x8*)alloc(9216 * 16);
  ushort* tb0  = (ushort*)alloc((size_t)N * FD * 2);
  ushort* tb1  = (ushort*)alloc((size_t)N * FD * 2);
  ushort* tba  = (ushort*)alloc((size_t)N * FD * 2);
  ushort* resb = (ushort*)alloc((size_t)N * FD * 2);

  int chunk = (E + NB - 1) / NB;
  dim3 gScan(256, 2);

  k_wsplit<<<36, 256, 0, stream>>>(W1, W2, W3, Wr, Wo, Whg, Wlg);
  k_hist<<<NB, 256, 0, stream>>>(src, dst, histD, histS, E, chunk);
  k_ssum<<<gScan, 256, 0, stream>>>(histD, histS, bsums);
  k_sscan<<<1, 256, 0, stream>>>(bsums);
  k_sapply<<<gScan, 256, 0, stream>>>(histD, histS, bsums);
  k_scatter<<<NB, 256, 0, stream>>>(src, dst, histD, histS, pk, srcS8, E, chunk);
  k_bucket_dst<<<NBINS, 256, 0, stream>>>(pk, histD, esrc, row_ptr, d_dst, N, E);
  k_bucket_src<<<NBINS, 256, 0, stream>>>(srcS8, histS, d_src, N, E);

  int gG = (N + 63) / 64;
  int nodeBlocks = (N + 63) / 64;
  int gA = NXCD * ((nodeBlocks + 1) / 2);  // XCD-pinned quarter-major

  const bf16x8* Wh1 = Whg;
  const bf16x8* Wh2 = Whg + 2048;
  const bf16x8* Wh3 = Whg + 4096;
  const bf16x8* Whr = Whg + 6144;
  const bf16x8* Who = Whg + 8192;
  const bf16x8* Wl1 = Wlg;
  const bf16x8* Wl2 = Wlg + 2048;
  const bf16x8* Wl3 = Wlg + 4096;
  const bf16x8* Wlr = Wlg + 6144;
  const bf16x8* Wlo = Wlg + 8192;

  // tb0 = bf16(d_src ⊙ (x@W1)); resb = bf16(x@Wr + br)
  k_gemm_dual<<<gG, 256, 0, stream>>>(x, Wh1, Wl1, d_src, Whr, Wlr, br, tb0, resb, N);
  // layer 1 conv epilogue + next scale: tba = d_src ⊙ relu(d_dst⊙Agg(tb0) + b1)
  k_agg4<false, true><<<gA, 256, 0, stream>>>(tb0, row_ptr, esrc, d_dst, b1, d_src,
                                              nullptr, tba, N, nodeBlocks);
  // tb1 = tba @ W2
  k_gemmB<FD, false, true><<<gG, 256, 0, stream>>>(tba, Wh2, Wl2, nullptr, tb1, N);
  // layer 2: tba = d_src ⊙ relu(d_dst⊙Agg(tb1) + b2)
  k_agg4<false, true><<<gA, 256, 0, stream>>>(tb1, row_ptr, esrc, d_dst, b2, d_src,
                                              nullptr, tba, N, nodeBlocks);
  // tb0 = tba @ W3
  k_gemmB<FD, false, true><<<gG, 256, 0, stream>>>(tba, Wh3, Wl3, nullptr, tb0, N);
  // layer 3: tba = relu(d_dst⊙Agg(tb0) + b3 + resb)
  k_agg4<true, false><<<gA, 256, 0, stream>>>(tb0, row_ptr, esrc, d_dst, b3, nullptr,
                                              resb, tba, N, nodeBlocks);
  // out = tba @ Wo + bo  (fp32)
  k_gemmB<CO, true, false><<<gG, 256, 0, stream>>>(tba, Who, Wlo, bo, out, N);
}

// Round 13
// 221.192 us; speedup vs baseline: 1.1456x; 1.0814x over previous
//
#include <hip/hip_runtime.h>
#include <cstdint>
#include <cstddef>

#define FD 128
#define CO 64
#define NB 256     // partition blocks
#define NBINS 256  // buckets (node>>8); requires N <= 65536

typedef short bf16x8 __attribute__((ext_vector_type(8)));
typedef float f32x4 __attribute__((ext_vector_type(4)));
typedef unsigned int uint32;
typedef unsigned char uint8;
typedef unsigned short ushort;

__device__ __forceinline__ ushort f2bf(float f) {
  unsigned u = __float_as_uint(f);
  unsigned r = u + 0x7fffu + ((u >> 16) & 1u);
  return (ushort)(r >> 16);
}
__device__ __forceinline__ float bf2f(ushort b) {
  return __uint_as_float((unsigned)b << 16);
}

// ---------------- CSR build: scan-based counting sort (no global atomics) ----------------

__global__ __launch_bounds__(256) void k_hist(const int* __restrict__ src,
                                              const int* __restrict__ dst,
                                              int* __restrict__ histD,
                                              int* __restrict__ histS,
                                              int E, int chunk) {
  __shared__ int hd[NBINS], hs[NBINS];
  int tid = threadIdx.x, blk = blockIdx.x;
  hd[tid] = 0;
  hs[tid] = 0;
  __syncthreads();
  int beg = blk * chunk;
  int end = min(E, beg + chunk);
  for (int e = beg + tid; e < end; e += 256) {
    atomicAdd(&hd[dst[e] >> 8], 1);
    atomicAdd(&hs[src[e] >> 8], 1);
  }
  __syncthreads();
  histD[tid * NB + blk] = hd[tid];  // bin-major layout
  histS[tid * NB + blk] = hs[tid];
}

__global__ __launch_bounds__(256) void k_ssum(int* __restrict__ a,
                                              int* __restrict__ b,
                                              int* __restrict__ bsums) {
  const int* p = blockIdx.y ? b : a;
  __shared__ int red[256];
  int tid = threadIdx.x;
  red[tid] = p[blockIdx.x * 256 + tid];
  __syncthreads();
  for (int o = 128; o > 0; o >>= 1) {
    if (tid < o) red[tid] += red[tid + o];
    __syncthreads();
  }
  if (tid == 0) bsums[blockIdx.y * 256 + blockIdx.x] = red[0];
}

__global__ __launch_bounds__(256) void k_sscan(int* __restrict__ bsums) {
  __shared__ int s[256];
  int tid = threadIdx.x;
  for (int r = 0; r < 2; r++) {
    int v = bsums[r * 256 + tid];
    s[tid] = v;
    __syncthreads();
    for (int o = 1; o < 256; o <<= 1) {
      int t = (tid >= o) ? s[tid - o] : 0;
      __syncthreads();
      s[tid] += t;
      __syncthreads();
    }
    bsums[r * 256 + tid] = s[tid] - v;  // exclusive
    __syncthreads();
  }
}

__global__ __launch_bounds__(256) void k_sapply(int* __restrict__ a,
                                                int* __restrict__ b,
                                                const int* __restrict__ bsums) {
  int* p = blockIdx.y ? b : a;
  int boff = bsums[blockIdx.y * 256 + blockIdx.x];
  __shared__ int s[256];
  int tid = threadIdx.x;
  int i = blockIdx.x * 256 + tid;
  int v = p[i];
  s[tid] = v;
  __syncthreads();
  for (int o = 1; o < 256; o <<= 1) {
    int t = (tid >= o) ? s[tid - o] : 0;
    __syncthreads();
    s[tid] += t;
    __syncthreads();
  }
  p[i] = boff + s[tid] - v;
}

__global__ __launch_bounds__(256) void k_scatter(const int* __restrict__ src,
                                                 const int* __restrict__ dst,
                                                 const int* __restrict__ offD,
                                                 const int* __restrict__ offS,
                                                 uint32* __restrict__ pk,
                                                 uint8* __restrict__ srcS8,
                                                 int E, int chunk) {
  __shared__ int runD[NBINS], runS[NBINS];
  int tid = threadIdx.x, blk = blockIdx.x;
  runD[tid] = offD[tid * NB + blk];
  runS[tid] = offS[tid * NB + blk];
  __syncthreads();
  int beg = blk * chunk;
  int end = min(E, beg + chunk);
  for (int e = beg + tid; e < end; e += 256) {
    int s = src[e], d = dst[e];
    int p = atomicAdd(&runD[d >> 8], 1);
    pk[p] = ((uint32)s << 8) | (uint32)(d & 255);
    int q = atomicAdd(&runS[s >> 8], 1);
    srcS8[q] = (uint8)(s & 255);
  }
}

// per-bucket: count deg_in -> row_ptr, d_dst; scatter src ids (uint16) into CSR esrc
__global__ __launch_bounds__(256) void k_bucket_dst(const uint32* __restrict__ pk,
                                                    const int* __restrict__ offD,
                                                    ushort* __restrict__ esrc,
                                                    int* __restrict__ row_ptr,
                                                    float* __restrict__ d_dst,
                                                    int N, int E) {
  __shared__ int cnt[NBINS], run[NBINS];
  int tid = threadIdx.x, bin = blockIdx.x;
  int start = offD[bin * NB];
  int end = (bin == NBINS - 1) ? E : offD[(bin + 1) * NB];
  cnt[tid] = 0;
  __syncthreads();
  for (int p = start + tid; p < end; p += 256) atomicAdd(&cnt[pk[p] & 255], 1);
  __syncthreads();
  int v = cnt[tid];
  run[tid] = v;
  __syncthreads();
  for (int o = 1; o < 256; o <<= 1) {
    int t = (tid >= o) ? run[tid - o] : 0;
    __syncthreads();
    run[tid] += t;
    __syncthreads();
  }
  int excl = run[tid] - v;
  int node = bin * 256 + tid;
  if (node < N) {
    row_ptr[node] = start + excl;
    d_dst[node] = rsqrtf((float)(v > 0 ? v : 1));
  }
  __syncthreads();
  run[tid] = start + excl;  // reuse as scatter cursor
  __syncthreads();
  for (int p = start + tid; p < end; p += 256) {
    uint32 v2 = pk[p];
    int slot = atomicAdd(&run[v2 & 255], 1);
    esrc[slot] = (ushort)(v2 >> 8);
  }
  if (bin == 0 && tid == 0) row_ptr[N] = E;
}

__global__ __launch_bounds__(256) void k_bucket_src(const uint8* __restrict__ srcS8,
                                                    const int* __restrict__ offS,
                                                    float* __restrict__ d_src,
                                                    int N, int E) {
  __shared__ int cnt[NBINS];
  int tid = threadIdx.x, bin = blockIdx.x;
  int start = offS[bin * NB];
  int end = (bin == NBINS - 1) ? E : offS[(bin + 1) * NB];
  cnt[tid] = 0;
  __syncthreads();
  for (int p = start + tid; p < end; p += 256) atomicAdd(&cnt[srcS8[p]], 1);
  __syncthreads();
  int node = bin * 256 + tid;
  if (node < N) {
    int v = cnt[tid];
    d_src[node] = rsqrtf((float)(v > 0 ? v : 1));
  }
}

// ---------------- weight pre-split: fp32 -> frag-packed bf16 hi/lo ----------------

__global__ __launch_bounds__(256) void k_wsplit(const float* __restrict__ W1,
                                                const float* __restrict__ W2,
                                                const float* __restrict__ W3,
                                                const float* __restrict__ Wr,
                                                const float* __restrict__ Wo,
                                                bf16x8* __restrict__ Whg,
                                                bf16x8* __restrict__ Wlg) {
  int idx = blockIdx.x * 256 + threadIdx.x;  // 9216 slots total
  if (idx >= 9216) return;
  int region = idx >> 11;
  if (idx >= 8192) region = 4;
  const float* W = (region == 0) ? W1 : (region == 1) ? W2 : (region == 2) ? W3
                   : (region == 3) ? Wr : Wo;
  int cols = (region < 4) ? FD : CO;
  int local = idx - region * 2048;
  int kc = local / cols, col = local - kc * cols;
  bf16x8 h, l;
#pragma unroll
  for (int j = 0; j < 8; j++) {
    float v = W[(size_t)(kc * 8 + j) * cols + col];
    ushort hb = f2bf(v);
    h[j] = (short)hb;
    l[j] = (short)f2bf(v - bf2f(hb));
  }
  Whg[idx] = h;
  Wlg[idx] = l;
}

// ---------------- dual GEMM: stage x once, two weight passes ----------------

__global__ __launch_bounds__(256) void k_gemm_dual(const float* __restrict__ x,
                                                   const bf16x8* __restrict__ Wh1,
                                                   const bf16x8* __restrict__ Wl1,
                                                   const float* __restrict__ d_src,
                                                   const bf16x8* __restrict__ Whr,
                                                   const bf16x8* __restrict__ Wlr,
                                                   const float* __restrict__ br,
                                                   ushort* __restrict__ out1,
                                                   ushort* __restrict__ out2,
                                                   int N) {
  __shared__ bf16x8 Ah[1024];  // [16 kc][64 row]
  int tid = threadIdx.x;
  int rowBase = blockIdx.x * 64;

#pragma unroll
  for (int t = 0; t < 4; t++) {
    int p = t * 256 + tid;
    int kc = p >> 6, row = p & 63;
    int gr = rowBase + row;
    bf16x8 h = {0, 0, 0, 0, 0, 0, 0, 0};
    if (gr < N) {
      const float4* A4 = (const float4*)(x + (size_t)gr * FD + kc * 8);
      float4 u = A4[0];
      float4 v = A4[1];
      float vals[8] = {u.x, u.y, u.z, u.w, v.x, v.y, v.z, v.w};
#pragma unroll
      for (int j = 0; j < 8; j++) h[j] = (short)f2bf(vals[j]);
    }
    Ah[kc * 64 + row] = h;
  }
  __syncthreads();

  int wv = tid >> 6, lane = tid & 63;
  int wr = (wv >> 1) * 32;
  int wc = (wv & 1) * 64;
  int lhi = lane >> 4, llo = lane & 15;

#pragma unroll
  for (int pass = 0; pass < 2; pass++) {
    const bf16x8* Wh = pass ? Whr : Wh1;
    const bf16x8* Wl = pass ? Wlr : Wl1;
    f32x4 acc[2][4] = {};
#pragma unroll
    for (int ks = 0; ks < 4; ks++) {
      int kcg = ks * 4 + lhi;
      int abase = kcg * 64 + wr + llo;
      bf16x8 a0 = Ah[abase];
      bf16x8 a1 = Ah[abase + 16];
      int bbase = kcg * FD + wc + llo;
#pragma unroll
      for (int nf = 0; nf < 4; nf++) {
        bf16x8 bh = Wh[bbase + nf * 16];
        bf16x8 bl = Wl[bbase + nf * 16];
        acc[0][nf] = __builtin_amdgcn_mfma_f32_16x16x32_bf16(a0, bh, acc[0][nf], 0, 0, 0);
        acc[1][nf] = __builtin_amdgcn_mfma_f32_16x16x32_bf16(a1, bh, acc[1][nf], 0, 0, 0);
        acc[0][nf] = __builtin_amdgcn_mfma_f32_16x16x32_bf16(a0, bl, acc[0][nf], 0, 0, 0);
        acc[1][nf] = __builtin_amdgcn_mfma_f32_16x16x32_bf16(a1, bl, acc[1][nf], 0, 0, 0);
      }
    }
#pragma unroll
    for (int nf = 0; nf < 4; nf++) {
      int col = wc + nf * 16 + llo;
      float bv = pass ? br[col] : 0.f;
#pragma unroll
      for (int mf = 0; mf < 2; mf++) {
#pragma unroll
        for (int r = 0; r < 4; r++) {
          int row = rowBase + wr + mf * 16 + lhi * 4 + r;
          if (row < N) {
            float v = acc[mf][nf][r];
            if (pass == 0) v *= d_src[row];
            else v += bv;
            ushort* o = pass ? out2 : out1;
            o[(size_t)row * FD + col] = f2bf(v);
          }
        }
      }
    }
  }
}

// ---------------- fused agg + GEMM (1024 thr = 16 waves; 1 node per 16-lane subgroup) ----------------
// Gather: 64 sub-groups of 16 lanes, one node each; 16-deep edge batch
//   (16 x uint4 = 256 B/lane in flight). Epilogue (×d_dst + bias [+res] relu
//   [×d_src]) -> bf16x8 -> swizzled LDS.
// GEMM: 64xNCW, 16 waves as 4(row)x4(col); wave-tile 16 x NCW/4.

template <int NCW, bool RES, bool NEXTSCALE, bool BIASOUT, bool OUTBF16>
__global__ __launch_bounds__(1024) void k_aggemm(const ushort* __restrict__ h,
                                                 const int* __restrict__ row_ptr,
                                                 const ushort* __restrict__ esrc,
                                                 const float* __restrict__ d_dst,
                                                 const float* __restrict__ bias_in,
                                                 const float* __restrict__ d_src,
                                                 const ushort* __restrict__ res,
                                                 const bf16x8* __restrict__ Wh,
                                                 const bf16x8* __restrict__ Wl,
                                                 const float* __restrict__ bias_out,
                                                 void* __restrict__ outv, int N) {
  constexpr int NF = NCW / 64;  // col-frags per wave (128->2, 64->1)
  __shared__ bf16x8 Alds[1024]; // 64 rows x 16 swizzled 16B slots, 16KB
  int tid = threadIdx.x;
  int wv = tid >> 6, lane = tid & 63;
  int rowBase = blockIdx.x * 64;
  int sub = lane >> 4, sl = lane & 15;
  int r = wv * 4 + sub;          // node slot 0..63 owned by this subgroup
  int gr = rowBase + r;
  const uint4* h16 = (const uint4*)h;

  // bias for features [8*sl, 8*sl+8)
  float4 bA = ((const float4*)bias_in)[sl * 2];
  float4 bB = ((const float4*)bias_in)[sl * 2 + 1];
  float bia[8] = {bA.x, bA.y, bA.z, bA.w, bB.x, bB.y, bB.z, bB.w};

  float val[8];
#pragma unroll
  for (int j = 0; j < 8; j++) val[j] = 0.f;

  if (gr < N) {
    int beg = row_ptr[gr], end = row_ptr[gr + 1];
    float a[8] = {0.f, 0.f, 0.f, 0.f, 0.f, 0.f, 0.f, 0.f};
    int e = beg;
    // full 16-deep batches
    for (; e + 16 <= end; e += 16) {
      int s[16];
#pragma unroll
      for (int j = 0; j < 16; j++) s[j] = esrc[e + j];
      uint4 v[16];
#pragma unroll
      for (int j = 0; j < 16; j++) v[j] = h16[(size_t)s[j] * 16 + sl];
#pragma unroll
      for (int j = 0; j < 16; j++) {
        a[0] += bf2f((ushort)(v[j].x & 0xffff));
        a[1] += bf2f((ushort)(v[j].x >> 16));
        a[2] += bf2f((ushort)(v[j].y & 0xffff));
        a[3] += bf2f((ushort)(v[j].y >> 16));
        a[4] += bf2f((ushort)(v[j].z & 0xffff));
        a[5] += bf2f((ushort)(v[j].z >> 16));
        a[6] += bf2f((ushort)(v[j].w & 0xffff));
        a[7] += bf2f((ushort)(v[j].w >> 16));
      }
    }
    // masked remainder batch (cnt in 1..15)
    if (e < end) {
      int cnt = end - e;
      int s[16];
#pragma unroll
      for (int j = 0; j < 16; j++) s[j] = (j < cnt) ? (int)esrc[e + j] : 0;
      uint4 v[16];
#pragma unroll
      for (int j = 0; j < 16; j++)
        if (j < cnt) v[j] = h16[(size_t)s[j] * 16 + sl];
#pragma unroll
      for (int j = 0; j < 16; j++) {
        if (j < cnt) {
          a[0] += bf2f((ushort)(v[j].x & 0xffff));
          a[1] += bf2f((ushort)(v[j].x >> 16));
          a[2] += bf2f((ushort)(v[j].y & 0xffff));
          a[3] += bf2f((ushort)(v[j].y >> 16));
          a[4] += bf2f((ushort)(v[j].z & 0xffff));
          a[5] += bf2f((ushort)(v[j].z >> 16));
          a[6] += bf2f((ushort)(v[j].w & 0xffff));
          a[7] += bf2f((ushort)(v[j].w >> 16));
        }
      }
    }
    float d = d_dst[gr];
#pragma unroll
    for (int j = 0; j < 8; j++) val[j] = a[j] * d + bia[j];
    if (RES) {
      uint4 rv = ((const uint4*)res)[(size_t)gr * 16 + sl];
      val[0] += bf2f((ushort)(rv.x & 0xffff));
      val[1] += bf2f((ushort)(rv.x >> 16));
      val[2] += bf2f((ushort)(rv.y & 0xffff));
      val[3] += bf2f((ushort)(rv.y >> 16));
      val[4] += bf2f((ushort)(rv.z & 0xffff));
      val[5] += bf2f((ushort)(rv.z >> 16));
      val[6] += bf2f((ushort)(rv.w & 0xffff));
      val[7] += bf2f((ushort)(rv.w >> 16));
    }
#pragma unroll
    for (int j = 0; j < 8; j++) val[j] = fmaxf(val[j], 0.f);
    if (NEXTSCALE) {
      float sc = d_src[gr];
#pragma unroll
      for (int j = 0; j < 8; j++) val[j] *= sc;
    }
  }
  bf16x8 o;
#pragma unroll
  for (int j = 0; j < 8; j++) o[j] = (short)f2bf(val[j]);
  Alds[r * 16 + (sl ^ (r & 7))] = o;
  __syncthreads();

  // ---- GEMM phase: 16 waves as 4 (rows) x 4 (cols); wave-tile 16 x NCW/4 ----
  int wr = (wv >> 2) * 16;
  int wc = (wv & 3) * (NCW / 4);
  int lhi = lane >> 4, llo = lane & 15;
  f32x4 acc[NF] = {};

#pragma unroll
  for (int ks = 0; ks < 4; ks++) {
    int kcg = ks * 4 + lhi;
    int row0 = wr + llo;
    bf16x8 a0 = Alds[row0 * 16 + (kcg ^ (row0 & 7))];
    int bbase = kcg * NCW + wc + llo;
#pragma unroll
    for (int nf = 0; nf < NF; nf++) {
      bf16x8 bh = Wh[bbase + nf * 16];
      bf16x8 bl = Wl[bbase + nf * 16];
      acc[nf] = __builtin_amdgcn_mfma_f32_16x16x32_bf16(a0, bh, acc[nf], 0, 0, 0);
      acc[nf] = __builtin_amdgcn_mfma_f32_16x16x32_bf16(a0, bl, acc[nf], 0, 0, 0);
    }
  }

  // epilogue: C/D layout col=lane&15, row=(lane>>4)*4+reg (offset wr)
#pragma unroll
  for (int nf = 0; nf < NF; nf++) {
    int col = wc + nf * 16 + llo;
    float bv = BIASOUT ? bias_out[col] : 0.f;
#pragma unroll
    for (int rr = 0; rr < 4; rr++) {
      int row = rowBase + wr + lhi * 4 + rr;
      if (row < N) {
        float v = acc[nf][rr] + bv;
        if (OUTBF16)
          ((ushort*)outv)[(size_t)row * NCW + col] = f2bf(v);
        else
          ((float*)outv)[(size_t)row * NCW + col] = v;
      }
    }
  }
}

// ---------------- launch ----------------

extern "C" void kernel_launch(void* const* d_in, const int* in_sizes, int n_in,
                              void* d_out, int out_size, void* d_ws, size_t ws_size,
                              hipStream_t stream) {
  (void)n_in; (void)out_size; (void)ws_size;
  const float* x  = (const float*)d_in[0];
  const int*   src = (const int*)d_in[1];
  const int*   dst = (const int*)d_in[2];
  const float* W1 = (const float*)d_in[3];
  const float* b1 = (const float*)d_in[4];
  const float* W2 = (const float*)d_in[5];
  const float* b2 = (const float*)d_in[6];
  const float* W3 = (const float*)d_in[7];
  const float* b3 = (const float*)d_in[8];
  const float* Wr = (const float*)d_in[9];
  const float* br = (const float*)d_in[10];
  const float* Wo = (const float*)d_in[11];
  const float* bo = (const float*)d_in[12];
  float* out = (float*)d_out;

  const int N = in_sizes[0] / FD;
  const int E = in_sizes[1];

  char* ws = (char*)d_ws;
  size_t off = 0;
  auto alloc = [&](size_t bytes) -> void* {
    void* p = ws + off;
    off += (bytes + 255) & ~size_t(255);
    return p;
  };
  int* histD   = (int*)alloc((size_t)NBINS * NB * 4);
  int* histS   = (int*)alloc((size_t)NBINS * NB * 4);
  int* bsums   = (int*)alloc(2 * 256 * 4);
  uint32* pk   = (uint32*)alloc((size_t)E * 4);
  uint8* srcS8 = (uint8*)alloc((size_t)E);
  ushort* esrc = (ushort*)alloc((size_t)E * 2);
  int* row_ptr = (int*)alloc((size_t)(N + 1) * 4);
  float* d_src = (float*)alloc((size_t)N * 4);
  float* d_dst = (float*)alloc((size_t)N * 4);
  bf16x8* Whg  = (bf16x8*)alloc(9216 * 16);
  bf16x8* Wlg  = (bf16x8*)alloc(9216 * 16);
  ushort* tb0  = (ushort*)alloc((size_t)N * FD * 2);
  ushort* tb1  = (ushort*)alloc((size_t)N * FD * 2);
  ushort* resb = (ushort*)alloc((size_t)N * FD * 2);

  int chunk = (E + NB - 1) / NB;
  dim3 gScan(256, 2);

  k_wsplit<<<36, 256, 0, stream>>>(W1, W2, W3, Wr, Wo, Whg, Wlg);
  k_hist<<<NB, 256, 0, stream>>>(src, dst, histD, histS, E, chunk);
  k_ssum<<<gScan, 256, 0, stream>>>(histD, histS, bsums);
  k_sscan<<<1, 256, 0, stream>>>(bsums);
  k_sapply<<<gScan, 256, 0, stream>>>(histD, histS, bsums);
  k_scatter<<<NB, 256, 0, stream>>>(src, dst, histD, histS, pk, srcS8, E, chunk);
  k_bucket_dst<<<NBINS, 256, 0, stream>>>(pk, histD, esrc, row_ptr, d_dst, N, E);
  k_bucket_src<<<NBINS, 256, 0, stream>>>(srcS8, histS, d_src, N, E);

  int gG = (N + 63) / 64;

  const bf16x8* Wh1 = Whg;
  const bf16x8* Wh2 = Whg + 2048;
  const bf16x8* Wh3 = Whg + 4096;
  const bf16x8* Whr = Whg + 6144;
  const bf16x8* Who = Whg + 8192;
  const bf16x8* Wl1 = Wlg;
  const bf16x8* Wl2 = Wlg + 2048;
  const bf16x8* Wl3 = Wlg + 4096;
  const bf16x8* Wlr = Wlg + 6144;
  const bf16x8* Wlo = Wlg + 8192;

  // tb0 = bf16(d_src ⊙ (x@W1)); resb = bf16(x@Wr + br)
  k_gemm_dual<<<gG, 256, 0, stream>>>(x, Wh1, Wl1, d_src, Whr, Wlr, br, tb0, resb, N);
  // tb1 = bf16( (d_src ⊙ relu(d_dst⊙Agg(tb0) + b1)) @ W2 )
  k_aggemm<FD, false, true, false, true><<<gG, 1024, 0, stream>>>(
      tb0, row_ptr, esrc, d_dst, b1, d_src, nullptr, Wh2, Wl2, nullptr, tb1, N);
  // tb0 = bf16( (d_src ⊙ relu(d_dst⊙Agg(tb1) + b2)) @ W3 )
  k_aggemm<FD, false, true, false, true><<<gG, 1024, 0, stream>>>(
      tb1, row_ptr, esrc, d_dst, b2, d_src, nullptr, Wh3, Wl3, nullptr, tb0, N);
  // out = fp32( relu(d_dst⊙Agg(tb0) + b3 + res) @ Wo + bo )
  k_aggemm<CO, true, false, true, false><<<gG, 1024, 0, stream>>>(
      tb0, row_ptr, esrc, d_dst, b3, nullptr, resb, Who, Wlo, bo, out, N);
}

// Round 14
// 203.326 us; speedup vs baseline: 1.2463x; 1.0879x over previous
//
#include <hip/hip_runtime.h>
#include <cstdint>
#include <cstddef>

#define FD 128
#define CO 64
#define NB 256     // partition blocks
#define NBINS 256  // buckets (node>>8); requires N <= 65536

typedef short bf16x8 __attribute__((ext_vector_type(8)));
typedef float f32x4 __attribute__((ext_vector_type(4)));
typedef unsigned int uint32;
typedef unsigned char uint8;
typedef unsigned short ushort;

__device__ __forceinline__ ushort f2bf(float f) {
  unsigned u = __float_as_uint(f);
  unsigned r = u + 0x7fffu + ((u >> 16) & 1u);
  return (ushort)(r >> 16);
}
__device__ __forceinline__ float bf2f(ushort b) {
  return __uint_as_float((unsigned)b << 16);
}

// ---------------- CSR build: scan-based counting sort (no global atomics) ----------------

__global__ __launch_bounds__(256) void k_hist(const int* __restrict__ src,
                                              const int* __restrict__ dst,
                                              int* __restrict__ histD,
                                              int* __restrict__ histS,
                                              int E, int chunk) {
  __shared__ int hd[NBINS], hs[NBINS];
  int tid = threadIdx.x, blk = blockIdx.x;
  hd[tid] = 0;
  hs[tid] = 0;
  __syncthreads();
  int beg = blk * chunk;
  int end = min(E, beg + chunk);
  for (int e = beg + tid; e < end; e += 256) {
    atomicAdd(&hd[dst[e] >> 8], 1);
    atomicAdd(&hs[src[e] >> 8], 1);
  }
  __syncthreads();
  histD[tid * NB + blk] = hd[tid];  // bin-major layout
  histS[tid * NB + blk] = hs[tid];
}

__global__ __launch_bounds__(256) void k_ssum(int* __restrict__ a,
                                              int* __restrict__ b,
                                              int* __restrict__ bsums) {
  const int* p = blockIdx.y ? b : a;
  __shared__ int red[256];
  int tid = threadIdx.x;
  red[tid] = p[blockIdx.x * 256 + tid];
  __syncthreads();
  for (int o = 128; o > 0; o >>= 1) {
    if (tid < o) red[tid] += red[tid + o];
    __syncthreads();
  }
  if (tid == 0) bsums[blockIdx.y * 256 + blockIdx.x] = red[0];
}

__global__ __launch_bounds__(256) void k_sscan(int* __restrict__ bsums) {
  __shared__ int s[256];
  int tid = threadIdx.x;
  for (int r = 0; r < 2; r++) {
    int v = bsums[r * 256 + tid];
    s[tid] = v;
    __syncthreads();
    for (int o = 1; o < 256; o <<= 1) {
      int t = (tid >= o) ? s[tid - o] : 0;
      __syncthreads();
      s[tid] += t;
      __syncthreads();
    }
    bsums[r * 256 + tid] = s[tid] - v;  // exclusive
    __syncthreads();
  }
}

__global__ __launch_bounds__(256) void k_sapply(int* __restrict__ a,
                                                int* __restrict__ b,
                                                const int* __restrict__ bsums) {
  int* p = blockIdx.y ? b : a;
  int boff = bsums[blockIdx.y * 256 + blockIdx.x];
  __shared__ int s[256];
  int tid = threadIdx.x;
  int i = blockIdx.x * 256 + tid;
  int v = p[i];
  s[tid] = v;
  __syncthreads();
  for (int o = 1; o < 256; o <<= 1) {
    int t = (tid >= o) ? s[tid - o] : 0;
    __syncthreads();
    s[tid] += t;
    __syncthreads();
  }
  p[i] = boff + s[tid] - v;
}

__global__ __launch_bounds__(256) void k_scatter(const int* __restrict__ src,
                                                 const int* __restrict__ dst,
                                                 const int* __restrict__ offD,
                                                 const int* __restrict__ offS,
                                                 uint32* __restrict__ pk,
                                                 uint8* __restrict__ srcS8,
                                                 int E, int chunk) {
  __shared__ int runD[NBINS], runS[NBINS];
  int tid = threadIdx.x, blk = blockIdx.x;
  runD[tid] = offD[tid * NB + blk];
  runS[tid] = offS[tid * NB + blk];
  __syncthreads();
  int beg = blk * chunk;
  int end = min(E, beg + chunk);
  for (int e = beg + tid; e < end; e += 256) {
    int s = src[e], d = dst[e];
    int p = atomicAdd(&runD[d >> 8], 1);
    pk[p] = ((uint32)s << 8) | (uint32)(d & 255);
    int q = atomicAdd(&runS[s >> 8], 1);
    srcS8[q] = (uint8)(s & 255);
  }
}

// merged per-bucket pass: grid.y==0 -> dst side (row_ptr, d_dst, CSR esrc);
//                         grid.y==1 -> src side (d_src)
__global__ __launch_bounds__(256) void k_bucket(const uint32* __restrict__ pk,
                                                const int* __restrict__ offD,
                                                const uint8* __restrict__ srcS8,
                                                const int* __restrict__ offS,
                                                ushort* __restrict__ esrc,
                                                int* __restrict__ row_ptr,
                                                float* __restrict__ d_dst,
                                                float* __restrict__ d_src,
                                                int N, int E) {
  __shared__ int cnt[NBINS], run[NBINS];
  int tid = threadIdx.x, bin = blockIdx.x;
  if (blockIdx.y == 0) {
    int start = offD[bin * NB];
    int end = (bin == NBINS - 1) ? E : offD[(bin + 1) * NB];
    cnt[tid] = 0;
    __syncthreads();
    for (int p = start + tid; p < end; p += 256) atomicAdd(&cnt[pk[p] & 255], 1);
    __syncthreads();
    int v = cnt[tid];
    run[tid] = v;
    __syncthreads();
    for (int o = 1; o < 256; o <<= 1) {
      int t = (tid >= o) ? run[tid - o] : 0;
      __syncthreads();
      run[tid] += t;
      __syncthreads();
    }
    int excl = run[tid] - v;
    int node = bin * 256 + tid;
    if (node < N) {
      row_ptr[node] = start + excl;
      d_dst[node] = rsqrtf((float)(v > 0 ? v : 1));
    }
    __syncthreads();
    run[tid] = start + excl;  // reuse as scatter cursor
    __syncthreads();
    for (int p = start + tid; p < end; p += 256) {
      uint32 v2 = pk[p];
      int slot = atomicAdd(&run[v2 & 255], 1);
      esrc[slot] = (ushort)(v2 >> 8);
    }
    if (bin == 0 && tid == 0) row_ptr[N] = E;
  } else {
    int start = offS[bin * NB];
    int end = (bin == NBINS - 1) ? E : offS[(bin + 1) * NB];
    cnt[tid] = 0;
    __syncthreads();
    for (int p = start + tid; p < end; p += 256) atomicAdd(&cnt[srcS8[p]], 1);
    __syncthreads();
    int node = bin * 256 + tid;
    if (node < N) {
      int v = cnt[tid];
      d_src[node] = rsqrtf((float)(v > 0 ? v : 1));
    }
  }
}

// ---------------- weight pre-split: fp32 -> frag-packed bf16 hi/lo ----------------

__global__ __launch_bounds__(256) void k_wsplit(const float* __restrict__ W1,
                                                const float* __restrict__ W2,
                                                const float* __restrict__ W3,
                                                const float* __restrict__ Wr,
                                                const float* __restrict__ Wo,
                                                bf16x8* __restrict__ Whg,
                                                bf16x8* __restrict__ Wlg) {
  int idx = blockIdx.x * 256 + threadIdx.x;  // 9216 slots total
  if (idx >= 9216) return;
  int region = idx >> 11;
  if (idx >= 8192) region = 4;
  const float* W = (region == 0) ? W1 : (region == 1) ? W2 : (region == 2) ? W3
                   : (region == 3) ? Wr : Wo;
  int cols = (region < 4) ? FD : CO;
  int local = idx - region * 2048;
  int kc = local / cols, col = local - kc * cols;
  bf16x8 h, l;
#pragma unroll
  for (int j = 0; j < 8; j++) {
    float v = W[(size_t)(kc * 8 + j) * cols + col];
    ushort hb = f2bf(v);
    h[j] = (short)hb;
    l[j] = (short)f2bf(v - bf2f(hb));
  }
  Whg[idx] = h;
  Wlg[idx] = l;
}

// ---------------- dual GEMM: stage x once, two weight passes ----------------

__global__ __launch_bounds__(256) void k_gemm_dual(const float* __restrict__ x,
                                                   const bf16x8* __restrict__ Wh1,
                                                   const bf16x8* __restrict__ Wl1,
                                                   const float* __restrict__ d_src,
                                                   const bf16x8* __restrict__ Whr,
                                                   const bf16x8* __restrict__ Wlr,
                                                   const float* __restrict__ br,
                                                   ushort* __restrict__ out1,
                                                   ushort* __restrict__ out2,
                                                   int N) {
  __shared__ bf16x8 Ah[1024];  // [16 kc][64 row]
  int tid = threadIdx.x;
  int rowBase = blockIdx.x * 64;

#pragma unroll
  for (int t = 0; t < 4; t++) {
    int p = t * 256 + tid;
    int kc = p >> 6, row = p & 63;
    int gr = rowBase + row;
    bf16x8 h = {0, 0, 0, 0, 0, 0, 0, 0};
    if (gr < N) {
      const float4* A4 = (const float4*)(x + (size_t)gr * FD + kc * 8);
      float4 u = A4[0];
      float4 v = A4[1];
      float vals[8] = {u.x, u.y, u.z, u.w, v.x, v.y, v.z, v.w};
#pragma unroll
      for (int j = 0; j < 8; j++) h[j] = (short)f2bf(vals[j]);
    }
    Ah[kc * 64 + row] = h;
  }
  __syncthreads();

  int wv = tid >> 6, lane = tid & 63;
  int wr = (wv >> 1) * 32;
  int wc = (wv & 1) * 64;
  int lhi = lane >> 4, llo = lane & 15;

#pragma unroll
  for (int pass = 0; pass < 2; pass++) {
    const bf16x8* Wh = pass ? Whr : Wh1;
    const bf16x8* Wl = pass ? Wlr : Wl1;
    f32x4 acc[2][4] = {};
#pragma unroll
    for (int ks = 0; ks < 4; ks++) {
      int kcg = ks * 4 + lhi;
      int abase = kcg * 64 + wr + llo;
      bf16x8 a0 = Ah[abase];
      bf16x8 a1 = Ah[abase + 16];
      int bbase = kcg * FD + wc + llo;
#pragma unroll
      for (int nf = 0; nf < 4; nf++) {
        bf16x8 bh = Wh[bbase + nf * 16];
        bf16x8 bl = Wl[bbase + nf * 16];
        acc[0][nf] = __builtin_amdgcn_mfma_f32_16x16x32_bf16(a0, bh, acc[0][nf], 0, 0, 0);
        acc[1][nf] = __builtin_amdgcn_mfma_f32_16x16x32_bf16(a1, bh, acc[1][nf], 0, 0, 0);
        acc[0][nf] = __builtin_amdgcn_mfma_f32_16x16x32_bf16(a0, bl, acc[0][nf], 0, 0, 0);
        acc[1][nf] = __builtin_amdgcn_mfma_f32_16x16x32_bf16(a1, bl, acc[1][nf], 0, 0, 0);
      }
    }
#pragma unroll
    for (int nf = 0; nf < 4; nf++) {
      int col = wc + nf * 16 + llo;
      float bv = pass ? br[col] : 0.f;
#pragma unroll
      for (int mf = 0; mf < 2; mf++) {
#pragma unroll
        for (int r = 0; r < 4; r++) {
          int row = rowBase + wr + mf * 16 + lhi * 4 + r;
          if (row < N) {
            float v = acc[mf][nf][r];
            if (pass == 0) v *= d_src[row];
            else v += bv;
            ushort* o = pass ? out2 : out1;
            o[(size_t)row * FD + col] = f2bf(v);
          }
        }
      }
    }
  }
}

// ---------------- fused agg + GEMM (512 thr = 8 waves; round-10 structure) ----------------
// Gather: wave splits into 4 sub-groups of 16 lanes; each sub-group gathers one
//   row with uint4 (8-feature) loads/lane; 8 rows/wave = 2 sequential quads;
//   8-deep edge batch. Epilogue (×d_dst + bias [+res] relu [×d_src]) ->
//   bf16x8 -> swizzled LDS (slot = sl ^ (r&7)).
// GEMM: 64xNCW, 8 waves as 2(row)x4(col); wave-tile 32 x NCW/4.

template <int NCW, bool RES, bool NEXTSCALE, bool BIASOUT, bool OUTBF16>
__global__ __launch_bounds__(512) void k_aggemm(const ushort* __restrict__ h,
                                                const int* __restrict__ row_ptr,
                                                const ushort* __restrict__ esrc,
                                                const float* __restrict__ d_dst,
                                                const float* __restrict__ bias_in,
                                                const float* __restrict__ d_src,
                                                const ushort* __restrict__ res,
                                                const bf16x8* __restrict__ Wh,
                                                const bf16x8* __restrict__ Wl,
                                                const float* __restrict__ bias_out,
                                                void* __restrict__ outv, int N) {
  constexpr int NF = NCW / 64;  // col-frags per wave (128->2, 64->1)
  __shared__ bf16x8 Alds[1024]; // 64 rows x 16 swizzled 16B slots, 16KB
  int tid = threadIdx.x;
  int wv = tid >> 6, lane = tid & 63;
  int rowBase = blockIdx.x * 64;
  int sub = lane >> 4, sl = lane & 15;
  const uint4* h16 = (const uint4*)h;

  // bias for features [8*sl, 8*sl+8)
  float4 bA = ((const float4*)bias_in)[sl * 2];
  float4 bB = ((const float4*)bias_in)[sl * 2 + 1];
  float bia[8] = {bA.x, bA.y, bA.z, bA.w, bB.x, bB.y, bB.z, bB.w};

  // ---- gather: 2 sequential row-quads ----
  for (int rq = 0; rq < 2; rq++) {
    int r = wv * 8 + rq * 4 + sub;
    int gr = rowBase + r;
    float a[8] = {0.f, 0.f, 0.f, 0.f, 0.f, 0.f, 0.f, 0.f};
    float val[8];
    if (gr < N) {
      int beg = row_ptr[gr], end = row_ptr[gr + 1];
      int e = beg;
      for (; e + 8 <= end; e += 8) {
        int s[8];
#pragma unroll
        for (int j = 0; j < 8; j++) s[j] = esrc[e + j];
        uint4 v[8];
#pragma unroll
        for (int j = 0; j < 8; j++) v[j] = h16[(size_t)s[j] * 16 + sl];
#pragma unroll
        for (int j = 0; j < 8; j++) {
          a[0] += bf2f((ushort)(v[j].x & 0xffff));
          a[1] += bf2f((ushort)(v[j].x >> 16));
          a[2] += bf2f((ushort)(v[j].y & 0xffff));
          a[3] += bf2f((ushort)(v[j].y >> 16));
          a[4] += bf2f((ushort)(v[j].z & 0xffff));
          a[5] += bf2f((ushort)(v[j].z >> 16));
          a[6] += bf2f((ushort)(v[j].w & 0xffff));
          a[7] += bf2f((ushort)(v[j].w >> 16));
        }
      }
      for (; e < end; e++) {
        uint4 v = h16[(size_t)esrc[e] * 16 + sl];
        a[0] += bf2f((ushort)(v.x & 0xffff));
        a[1] += bf2f((ushort)(v.x >> 16));
        a[2] += bf2f((ushort)(v.y & 0xffff));
        a[3] += bf2f((ushort)(v.y >> 16));
        a[4] += bf2f((ushort)(v.z & 0xffff));
        a[5] += bf2f((ushort)(v.z >> 16));
        a[6] += bf2f((ushort)(v.w & 0xffff));
        a[7] += bf2f((ushort)(v.w >> 16));
      }
      float d = d_dst[gr];
#pragma unroll
      for (int j = 0; j < 8; j++) val[j] = a[j] * d + bia[j];
      if (RES) {
        uint4 rv = ((const uint4*)res)[(size_t)gr * 16 + sl];
        val[0] += bf2f((ushort)(rv.x & 0xffff));
        val[1] += bf2f((ushort)(rv.x >> 16));
        val[2] += bf2f((ushort)(rv.y & 0xffff));
        val[3] += bf2f((ushort)(rv.y >> 16));
        val[4] += bf2f((ushort)(rv.z & 0xffff));
        val[5] += bf2f((ushort)(rv.z >> 16));
        val[6] += bf2f((ushort)(rv.w & 0xffff));
        val[7] += bf2f((ushort)(rv.w >> 16));
      }
#pragma unroll
      for (int j = 0; j < 8; j++) val[j] = fmaxf(val[j], 0.f);
      if (NEXTSCALE) {
        float sc = d_src[gr];
#pragma unroll
        for (int j = 0; j < 8; j++) val[j] *= sc;
      }
    } else {
#pragma unroll
      for (int j = 0; j < 8; j++) val[j] = 0.f;
    }
    bf16x8 o;
#pragma unroll
    for (int j = 0; j < 8; j++) o[j] = (short)f2bf(val[j]);
    Alds[r * 16 + (sl ^ (r & 7))] = o;
  }
  __syncthreads();

  // ---- GEMM phase: 8 waves as 2 (rows) x 4 (cols) ----
  int wr = (wv >> 2) * 32;
  int wc = (wv & 3) * (NCW / 4);
  int lhi = lane >> 4, llo = lane & 15;
  f32x4 acc[2][NF] = {};

#pragma unroll
  for (int ks = 0; ks < 4; ks++) {
    int kcg = ks * 4 + lhi;
    int row0 = wr + llo;
    int row1 = wr + 16 + llo;
    bf16x8 a0 = Alds[row0 * 16 + (kcg ^ (row0 & 7))];
    bf16x8 a1 = Alds[row1 * 16 + (kcg ^ (row1 & 7))];
    int bbase = kcg * NCW + wc + llo;
#pragma unroll
    for (int nf = 0; nf < NF; nf++) {
      bf16x8 bh = Wh[bbase + nf * 16];
      bf16x8 bl = Wl[bbase + nf * 16];
      acc[0][nf] = __builtin_amdgcn_mfma_f32_16x16x32_bf16(a0, bh, acc[0][nf], 0, 0, 0);
      acc[1][nf] = __builtin_amdgcn_mfma_f32_16x16x32_bf16(a1, bh, acc[1][nf], 0, 0, 0);
      acc[0][nf] = __builtin_amdgcn_mfma_f32_16x16x32_bf16(a0, bl, acc[0][nf], 0, 0, 0);
      acc[1][nf] = __builtin_amdgcn_mfma_f32_16x16x32_bf16(a1, bl, acc[1][nf], 0, 0, 0);
    }
  }

  // epilogue: C/D layout col=lane&15, row=(lane>>4)*4+reg
#pragma unroll
  for (int nf = 0; nf < NF; nf++) {
    int col = wc + nf * 16 + llo;
    float bv = BIASOUT ? bias_out[col] : 0.f;
#pragma unroll
    for (int mf = 0; mf < 2; mf++) {
#pragma unroll
      for (int r = 0; r < 4; r++) {
        int row = rowBase + wr + mf * 16 + lhi * 4 + r;
        if (row < N) {
          float v = acc[mf][nf][r] + bv;
          if (OUTBF16)
            ((ushort*)outv)[(size_t)row * NCW + col] = f2bf(v);
          else
            ((float*)outv)[(size_t)row * NCW + col] = v;
        }
      }
    }
  }
}

// ---------------- launch ----------------

extern "C" void kernel_launch(void* const* d_in, const int* in_sizes, int n_in,
                              void* d_out, int out_size, void* d_ws, size_t ws_size,
                              hipStream_t stream) {
  (void)n_in; (void)out_size; (void)ws_size;
  const float* x  = (const float*)d_in[0];
  const int*   src = (const int*)d_in[1];
  const int*   dst = (const int*)d_in[2];
  const float* W1 = (const float*)d_in[3];
  const float* b1 = (const float*)d_in[4];
  const float* W2 = (const float*)d_in[5];
  const float* b2 = (const float*)d_in[6];
  const float* W3 = (const float*)d_in[7];
  const float* b3 = (const float*)d_in[8];
  const float* Wr = (const float*)d_in[9];
  const float* br = (const float*)d_in[10];
  const float* Wo = (const float*)d_in[11];
  const float* bo = (const float*)d_in[12];
  float* out = (float*)d_out;

  const int N = in_sizes[0] / FD;
  const int E = in_sizes[1];

  char* ws = (char*)d_ws;
  size_t off = 0;
  auto alloc = [&](size_t bytes) -> void* {
    void* p = ws + off;
    off += (bytes + 255) & ~size_t(255);
    return p;
  };
  int* histD   = (int*)alloc((size_t)NBINS * NB * 4);
  int* histS   = (int*)alloc((size_t)NBINS * NB * 4);
  int* bsums   = (int*)alloc(2 * 256 * 4);
  uint32* pk   = (uint32*)alloc((size_t)E * 4);
  uint8* srcS8 = (uint8*)alloc((size_t)E);
  ushort* esrc = (ushort*)alloc((size_t)E * 2);
  int* row_ptr = (int*)alloc((size_t)(N + 1) * 4);
  float* d_src = (float*)alloc((size_t)N * 4);
  float* d_dst = (float*)alloc((size_t)N * 4);
  bf16x8* Whg  = (bf16x8*)alloc(9216 * 16);
  bf16x8* Wlg  = (bf16x8*)alloc(9216 * 16);
  ushort* tb0  = (ushort*)alloc((size_t)N * FD * 2);
  ushort* tb1  = (ushort*)alloc((size_t)N * FD * 2);
  ushort* resb = (ushort*)alloc((size_t)N * FD * 2);

  int chunk = (E + NB - 1) / NB;
  dim3 gScan(256, 2);
  dim3 gBucket(NBINS, 2);

  k_wsplit<<<36, 256, 0, stream>>>(W1, W2, W3, Wr, Wo, Whg, Wlg);
  k_hist<<<NB, 256, 0, stream>>>(src, dst, histD, histS, E, chunk);
  k_ssum<<<gScan, 256, 0, stream>>>(histD, histS, bsums);
  k_sscan<<<1, 256, 0, stream>>>(bsums);
  k_sapply<<<gScan, 256, 0, stream>>>(histD, histS, bsums);
  k_scatter<<<NB, 256, 0, stream>>>(src, dst, histD, histS, pk, srcS8, E, chunk);
  k_bucket<<<gBucket, 256, 0, stream>>>(pk, histD, srcS8, histS, esrc, row_ptr,
                                        d_dst, d_src, N, E);

  int gG = (N + 63) / 64;

  const bf16x8* Wh1 = Whg;
  const bf16x8* Wh2 = Whg + 2048;
  const bf16x8* Wh3 = Whg + 4096;
  const bf16x8* Whr = Whg + 6144;
  const bf16x8* Who = Whg + 8192;
  const bf16x8* Wl1 = Wlg;
  const bf16x8* Wl2 = Wlg + 2048;
  const bf16x8* Wl3 = Wlg + 4096;
  const bf16x8* Wlr = Wlg + 6144;
  const bf16x8* Wlo = Wlg + 8192;

  // tb0 = bf16(d_src ⊙ (x@W1)); resb = bf16(x@Wr + br)
  k_gemm_dual<<<gG, 256, 0, stream>>>(x, Wh1, Wl1, d_src, Whr, Wlr, br, tb0, resb, N);
  // tb1 = bf16( (d_src ⊙ relu(d_dst⊙Agg(tb0) + b1)) @ W2 )
  k_aggemm<FD, false, true, false, true><<<gG, 512, 0, stream>>>(
      tb0, row_ptr, esrc, d_dst, b1, d_src, nullptr, Wh2, Wl2, nullptr, tb1, N);
  // tb0 = bf16( (d_src ⊙ relu(d_dst⊙Agg(tb1) + b2)) @ W3 )
  k_aggemm<FD, false, true, false, true><<<gG, 512, 0, stream>>>(
      tb1, row_ptr, esrc, d_dst, b2, d_src, nullptr, Wh3, Wl3, nullptr, tb0, N);
  // out = fp32( relu(d_dst⊙Agg(tb0) + b3 + res) @ Wo + bo )
  k_aggemm<CO, true, false, true, false><<<gG, 512, 0, stream>>>(
      tb0, row_ptr, esrc, d_dst, b3, nullptr, resb, Who, Wlo, bo, out, N);
}